// Round 9
// baseline (1362.531 us; speedup 1.0000x reference)
//
#include <hip/hip_runtime.h>
#include <math.h>

#define V 30000
#define E 200
#define T 100
#define N 2048
#define NITER 100
#define KSTR 112          // padded K_TW row stride in ushorts (224 B, 16B-aligned)
#define EPS_OT 1e-16f
#define EPS_LOG 1e-12f

#define NBTW 40           // TW sinkhorn blocks
#define WPT 3             // K rows (words) per thread: 40*256*3 = 30720 >= V
#define NDT 8             // DT blocks (gated)
#define PSTR 64           // per-topic partial stride (floats): 40 used, 64 padded

// ws float offsets
#define OFF_KTW    0            // ushort[V*KSTR] bf16 word-major = 1,680,000 floats
#define OFF_KDT    1680000      // float[N*T]
#define OFF_WW     1884800      // V
#define OFF_DD     1914800      // N
#define OFF_TT     1916848      // 128
#define OFF_PM     1916976      // 128
#define OFF_PS     1917104      // 128
#define OFF_BTW    1917232      // V    softmax(word_weights)
#define OFF_BDT    1947232      // 128  softmax(topic_weights)
#define OFF_ACC    1947360      // NITER*T (legacy, still zeroed)
#define OFF_ACCDT  1957360      // NITER*T DT accumulators (gated)
#define OFF_VTW    1967360      // V
#define OFF_UDT    1997360      // N
#define OFF_UTW    1999408      // 128
#define OFF_VDT    1999536      // 128
#define OFF_DBL    1999664      // 16 floats = 8 doubles
#define OFF_FLAG   1999680      // int index: theta nonzero
#define OFF_KDTNZ  1999681      // int index: any K_DT nonzero
#define OFF_ARR    1999682      // int[2*NITER]: DT arrive counters
#define OFF_PART   2000000      // float[2][T][PSTR] double-buffered TW partials, topic-major
                                // sign bit of each value = iteration tag (k>>1)&1
#define OFF_FLG    2013312      // float[2][64] per-block iteration flags (sign-tagged),
                                // flag for iter k at buf[k&1], tag (k>>1)&1

#define LOBF(u) __uint_as_float((u) << 16)
#define HIBF(u) __uint_as_float((u) & 0xffff0000u)

typedef __attribute__((ext_vector_type(4))) float f32x4;

__device__ __forceinline__ unsigned short f2bf(float f) {
    unsigned int u = __float_as_uint(f);
    return (unsigned short)((u + 0x7fffu + ((u >> 16) & 1u)) >> 16);
}
__device__ __forceinline__ float bf2f(unsigned short h) {
    return __uint_as_float(((unsigned int)h) << 16);
}

__device__ __forceinline__ float brsum(float x, float* red8) {
    int tid = threadIdx.x;
    for (int o = 32; o; o >>= 1) x += __shfl_down(x, o, 64);
    __syncthreads();
    if ((tid & 63) == 0) red8[tid >> 6] = x;
    __syncthreads();
    return (red8[0] + red8[1]) + (red8[2] + red8[3]);
}

__device__ __forceinline__ void load_krow(const unsigned short* kg, int j, unsigned* ku) {
    const uint4* kp = (const uint4*)(kg + (size_t)j * KSTR);
    #pragma unroll
    for (int i = 0; i < 12; i++) {
        uint4 q = kp[i];
        ku[4*i] = q.x; ku[4*i+1] = q.y; ku[4*i+2] = q.z; ku[4*i+3] = q.w;
    }
    uint2 q2 = *(const uint2*)(((const unsigned*)kp) + 48);
    ku[48] = q2.x; ku[49] = q2.y;
}

// coherent (L1/L2-bypassing) memory ops: L3 is the cross-XCD coherence point.
__device__ __forceinline__ f32x4 ldg_coh4(const float* p) {
    f32x4 r;
    asm volatile("global_load_dwordx4 %0, %1, off sc0 sc1" : "=v"(r) : "v"(p) : "memory");
    return r;
}
__device__ __forceinline__ float ldg_coh1(const float* p) {
    float r;
    asm volatile("global_load_dword %0, %1, off sc0 sc1" : "=v"(r) : "v"(p) : "memory");
    return r;
}
__device__ __forceinline__ void stg_coh1(float* p, float v) {
    asm volatile("global_store_dword %0, %1, off sc0 sc1" :: "v"(p), "v"(v) : "memory");
}
__device__ __forceinline__ void wait_vm0() {
    asm volatile("s_waitcnt vmcnt(0)" ::: "memory");
    __builtin_amdgcn_sched_barrier(0);
}

// Poll one tagged flag word until its sign bit == ptag (tight loop, 4 B traffic).
__device__ __forceinline__ void poll_flag(const float* p, unsigned ptag) {
    while (true) {
        float f = ldg_coh1(p);
        wait_vm0();
        unsigned u = __float_as_uint(f);
        if (ptag ? (u >> 31) : !(u >> 31)) break;
    }
}

// Single bulk read of 20 partials (5 dwordx4) + magnitude sum (same tree as R4/R5).
__device__ __forceinline__ float read_sum20(const float* Pp) {
    f32x4 a0 = ldg_coh4(Pp + 0);
    f32x4 a1 = ldg_coh4(Pp + 4);
    f32x4 a2 = ldg_coh4(Pp + 8);
    f32x4 a3 = ldg_coh4(Pp + 12);
    f32x4 a4 = ldg_coh4(Pp + 16);
    wait_vm0();
    return (((fabsf(a0.x) + fabsf(a0.y)) + (fabsf(a0.z) + fabsf(a0.w)))
          + ((fabsf(a1.x) + fabsf(a1.y)) + (fabsf(a1.z) + fabsf(a1.w))))
         + (((fabsf(a2.x) + fabsf(a2.y)) + (fabsf(a2.z) + fabsf(a2.w)))
          + ((fabsf(a3.x) + fabsf(a3.y)) + (fabsf(a3.z) + fabsf(a3.w))))
         + ((fabsf(a4.x) + fabsf(a4.y)) + (fabsf(a4.z) + fabsf(a4.w)));
}

// legacy counter barrier (DT role only, 8 blocks)
__device__ __forceinline__ void gbar(int* ctr, int n, int tid) {
    __syncthreads();
    if (tid == 0) {
        __hip_atomic_fetch_add(ctr, 1, __ATOMIC_RELEASE, __HIP_MEMORY_SCOPE_AGENT);
        while (__hip_atomic_load(ctr, __ATOMIC_ACQUIRE, __HIP_MEMORY_SCOPE_AGENT) < n)
            __builtin_amdgcn_s_sleep(1);
    }
    __syncthreads();
}

__device__ __forceinline__ float agent_ldf(const float* p) {
    return __hip_atomic_load(p, __ATOMIC_RELAXED, __HIP_MEMORY_SCOPE_AGENT);
}

// ---------- zeroing + row norms + word-softmax partials + topic softmax ----------
__global__ void k_pre(const float* __restrict__ we, const float* __restrict__ de,
                      const float* __restrict__ te, const float* __restrict__ wwgt,
                      const float* __restrict__ twgt, float* ws) {
    __shared__ float red[256];
    int tid = threadIdx.x, b = blockIdx.x;
    int gid = b * 256 + tid;
    if (gid < 2 * NITER * T) ws[OFF_ACC + gid] = 0.f;      // ACC + ACCDT contiguous
    if (gid < 16) ws[OFF_DBL + gid] = 0.f;
    if (gid < 2) ((int*)ws)[OFF_FLAG + gid] = 0;
    if (gid < 2 * NITER) ((int*)ws)[OFF_ARR + gid] = 0;    // DT barrier counters
    if (gid < 2 * T * PSTR) ws[OFF_PART + gid] = __uint_as_float(0x80000000u); // tag=1 preset
    if (gid < 128) ws[OFF_FLG + gid] = __uint_as_float(0x80000000u); // flag preset tag=1
    {   // squared row norms
        int r = gid;
        const float* src = nullptr; float* dst = nullptr; int row = 0;
        if (r < V)              { src = we; dst = ws + OFF_WW; row = r; }
        else if (r < V + N)     { src = de; dst = ws + OFF_DD; row = r - V; }
        else if (r < V + N + T) { src = te; dst = ws + OFF_TT; row = r - V - N; }
        if (src) {
            const float4* p = (const float4*)(src + (size_t)row * E);
            float s = 0.f;
            #pragma unroll 10
            for (int i = 0; i < E / 4; i++) { float4 v = p[i]; s += v.x*v.x + v.y*v.y + v.z*v.z + v.w*v.w; }
            dst[row] = s;
        }
    }
    if (b < 118) {  // word-softmax partials
        int j = gid;
        float w = (j < V) ? wwgt[j] : -INFINITY;
        red[tid] = w; __syncthreads();
        for (int s = 128; s > 0; s >>= 1) { if (tid < s) red[tid] = fmaxf(red[tid], red[tid + s]); __syncthreads(); }
        float m = red[0]; __syncthreads();
        float e = (j < V) ? expf(w - m) : 0.f;
        red[tid] = e; __syncthreads();
        for (int s = 128; s > 0; s >>= 1) { if (tid < s) red[tid] += red[tid + s]; __syncthreads(); }
        if (tid == 0) { ws[OFF_PM + b] = m; ws[OFF_PS + b] = red[0]; }
    } else if (b == 120) {  // topic softmax -> b_dt
        float w = (tid < T) ? twgt[tid] : -INFINITY;
        red[tid] = w; __syncthreads();
        for (int s = 128; s > 0; s >>= 1) { if (tid < s) red[tid] = fmaxf(red[tid], red[tid + s]); __syncthreads(); }
        float m = red[0]; __syncthreads();
        float e = (tid < T) ? expf(w - m) : 0.f;
        red[tid] = e; __syncthreads();
        for (int s = 128; s > 0; s >>= 1) { if (tid < s) red[tid] += red[tid + s]; __syncthreads(); }
        if (tid < T) ws[OFF_BDT + tid] = e / red[0];
    }
}

// ---------- merge word-softmax partials -> b_tw ----------
__global__ void k_pre2(const float* __restrict__ wwgt, float* ws) {
    __shared__ float red[128];
    int tid = threadIdx.x, b = blockIdx.x;
    float m = (tid < 118) ? ws[OFF_PM + tid] : -INFINITY;
    if (tid < 128) red[tid] = m;
    __syncthreads();
    for (int s = 64; s > 0; s >>= 1) { if (tid < s) red[tid] = fmaxf(red[tid], red[tid + s]); __syncthreads(); }
    float mw = red[0]; __syncthreads();
    float p = (tid < 118) ? ws[OFF_PS + tid] * expf(ws[OFF_PM + tid] - mw) : 0.f;
    if (tid < 128) red[tid] = p;
    __syncthreads();
    for (int s = 64; s > 0; s >>= 1) { if (tid < s) red[tid] += red[tid + s]; __syncthreads(); }
    float Sw = red[0];
    int j = b * 256 + tid;
    if (j < V) ws[OFF_BTW + j] = expf(wwgt[j] - mw) / Sw;
}

// ---------- K_TW[j][t] = bf16(exp(-2*sqdist)), word-major stride KSTR ----------
__global__ void k_ktw(const float* __restrict__ we, const float* __restrict__ te, float* ws) {
    __shared__ float wt[8][256];
    __shared__ float tp[8][25];
    __shared__ float tts[25];
    int tid = threadIdx.x;
    int j0 = blockIdx.x * 256;
    int t0 = blockIdx.y * 25;
    int j = j0 + tid;
    int jl = (j < V) ? j : V - 1;
    float acc[25];
    #pragma unroll
    for (int i = 0; i < 25; i++) acc[i] = 0.f;
    if (tid < 25) tts[tid] = ws[OFF_TT + t0 + tid];
    for (int kk = 0; kk < E; kk += 8) {
        #pragma unroll
        for (int k = 0; k < 8; k++) wt[k][tid] = we[(size_t)jl * E + kk + k];
        if (tid < 200) { int i = tid >> 3; int k = tid & 7; tp[k][i] = te[(size_t)(t0 + i) * E + kk + k]; }
        __syncthreads();
        #pragma unroll
        for (int k = 0; k < 8; k++) {
            float w = wt[k][tid];
            #pragma unroll
            for (int i = 0; i < 25; i++) acc[i] += tp[k][i] * w;
        }
        __syncthreads();
    }
    if (j < V) {
        float wwj = ws[OFF_WW + j];
        unsigned short* kg = (unsigned short*)(ws + OFF_KTW);
        #pragma unroll
        for (int i = 0; i < 25; i++) {
            float M = tts[i] + wwj - 2.f * acc[i];
            kg[(size_t)j * KSTR + t0 + i] = f2bf(expf(-2.f * M));
        }
    }
}

// ---------- K_DT[n][t] = exp(-3*sqdist), fp32, + any-nonzero flag ----------
__global__ void k_kdt(const float* __restrict__ de, const float* __restrict__ te, float* ws) {
    int gid = blockIdx.x * 256 + threadIdx.x;
    if (gid >= N * T) return;
    int n = gid / T; int t = gid - n * T;
    const float4* dp  = (const float4*)(de + (size_t)n * E);
    const float4* tpp = (const float4*)(te + (size_t)t * E);
    float s = 0.f;
    #pragma unroll 10
    for (int i = 0; i < E / 4; i++) { float4 a = dp[i], b = tpp[i]; s += a.x*b.x + a.y*b.y + a.z*b.z + a.w*b.w; }
    float M = ws[OFF_DD + n] + ws[OFF_TT + t] - 2.f * s;
    float kv = expf(-3.f * M);
    ws[OFF_KDT + gid] = kv;
    unsigned long long m = __ballot(kv != 0.f);
    if (m && (threadIdx.x & 63) == 0) atomicOr(((int*)ws) + OFF_KDTNZ, 1);
}

// ---------- persistent fused sinkhorn (one-hop + cheap flags, no reducer) ----------
// blocks 0..NBTW-1      : TW sinkhorn, WPT=3 K-rows/thread in registers.
//   per iter: poll 40 tagged FLAG words (160 B/round, broadcast lines), then ONE
//   bulk coherent read of the 40x100 partials (16 KB, same lines for all blocks),
//   reduce locally (bit-identical tree) -> u, down-sweep, up-sweep, tagged partial
//   stores, __syncthreads (drains stores: vmcnt(0) before s_barrier), tid0 flag.
// blocks NBTW..NBTW+127 : bow total sum (free-running, bit-identical chunking)
// blocks NBTW+128..+135 : DT sinkhorn (gated on kdtnz) + fused DT epilogue
__global__ __launch_bounds__(256, 1) void k_sink(const float* __restrict__ bow, float* ws) {
    __shared__ float sm[256 * 26];
    __shared__ float pr[256];
    __shared__ float u_sh[100];
    __shared__ float red8[8];
    int tid = threadIdx.x, b = blockIdx.x;

    if (b >= NBTW && b < NBTW + 128) {    // ---- bow role ----
        const float4* b4 = (const float4*)bow;
        for (int k = 0; k < 96; k++) {
            size_t base = (size_t)k * 160000;
            float s = 0.f;
            for (int i = (b - NBTW) * 256 + tid; i < 160000; i += 128 * 256) {
                float4 x = b4[base + i]; s += (x.x + x.y) + (x.z + x.w);
            }
            float bs = brsum(s, red8);
            if (tid == 0) atomicAdd((double*)(ws + OFF_DBL) + 3, (double)bs);
        }
        return;
    }

    if (b >= NBTW + 128) {                // ---- DT role (gated) ----
        if (((volatile int*)ws)[OFF_KDTNZ] == 0) return;
        int* arr = ((int*)ws) + OFF_ARR;
        int d = (b - (NBTW + 128)) * 256 + tid;    // 0..2047
        const float* Kr = ws + OFF_KDT + (size_t)d * T;
        for (int k = 0; k < NITER; k++) {
            if (tid < T) u_sh[tid] = (k == 0) ? 0.f
                : ws[OFF_BDT + tid] / (agent_ldf(ws + OFF_ACCDT + (k - 1) * T + tid) + EPS_OT);
            __syncthreads();
            float u;
            if (k == 0) u = 1.f / N;
            else {
                float s = 0.f;
                #pragma unroll 4
                for (int t = 0; t < T; t++) s += Kr[t] * u_sh[t];
                u = (1.f / N) / (s + EPS_OT);
            }
            #pragma unroll
            for (int c = 0; c < 4; c++) {
                #pragma unroll
                for (int i = 0; i < 25; i++) sm[tid * 26 + i] = Kr[25 * c + i] * u;
                __syncthreads();
                int g = tid >> 5, tl = tid & 31;
                float s2 = 0.f;
                if (tl < 25) {
                    #pragma unroll 8
                    for (int q = 0; q < 32; q++) s2 += sm[(g * 32 + q) * 26 + tl];
                }
                pr[g * 32 + tl] = s2;
                __syncthreads();
                if (tid < 25) {
                    float r = 0.f;
                    #pragma unroll
                    for (int g2 = 0; g2 < 8; g2++) r += pr[g2 * 32 + tid];
                    atomicAdd(&ws[OFF_ACCDT + k * T + 25 * c + tid], r);
                }
                __syncthreads();
            }
            gbar(arr + NITER + k, NDT, tid);
        }
        if (tid < T) {
            float vf = ws[OFF_BDT + tid] / (agent_ldf(ws + OFF_ACCDT + (NITER - 1) * T + tid) + EPS_OT);
            u_sh[tid] = vf;
            if (b == NBTW + 128) ws[OFF_VDT + tid] = vf;
        }
        __syncthreads();
        float s = 0.f;
        #pragma unroll 4
        for (int t = 0; t < T; t++) s += Kr[t] * u_sh[t];
        float u = (1.f / N) / (s + EPS_OT);
        ws[OFF_UDT + d] = u;
        float ld = 0.f; int nz = 0;
        for (int t = 0; t < T; t++) {
            float kv = Kr[t];
            if (kv > 0.f) ld += u * kv * u_sh[t] * (-(1.f / 3.f) * logf(kv));
            if ((float)N * u * kv * u_sh[t] != 0.f) nz = 1;
        }
        float ldb = brsum(ld, red8);
        if (tid == 0) atomicAdd((double*)(ws + OFF_DBL) + 1, (double)ldb);
        if (nz) atomicOr(((int*)ws) + OFF_FLAG, 1);
        return;
    }

    // ---- TW role ----
    const unsigned short* kg = (const unsigned short*)(ws + OFF_KTW);
    unsigned ku[WPT][50];
    float bj[WPT];
    #pragma unroll
    for (int w = 0; w < WPT; w++) {
        int j = (b * WPT + w) * 256 + tid;
        bool oob = (j >= V);
        load_krow(kg, oob ? V - 1 : j, ku[w]);
        if (oob) {
            #pragma unroll
            for (int q = 0; q < 50; q++) ku[w][q] = 0;
        }
        bj[w] = oob ? 0.f : ws[OFF_BTW + j];
    }
    float v[WPT];
    #pragma unroll
    for (int w = 0; w < WPT; w++) v[w] = 0.f;

    for (int k = 0; k < NITER; k++) {
        // ---- u for iter k: poll flags of iter k-1, bulk-read partials, reduce ----
        if (k == 0) {
            if (tid < T) u_sh[tid] = 0.01f;
            __syncthreads();
        } else {
            if (tid < NBTW)
                poll_flag(ws + OFF_FLG + (size_t)((k - 1) & 1) * 64 + tid, ((k - 1) >> 1) & 1);
            __syncthreads();
            float rs = 0.f;
            if (tid < 2 * T) {
                int t = tid >> 1, half = tid & 1;
                const float* Pp = ws + OFF_PART + (size_t)((k - 1) & 1) * (T * PSTR)
                                  + t * PSTR + half * 20;
                rs = read_sum20(Pp);
            }
            pr[tid] = rs;
            __syncthreads();
            if (tid < T) u_sh[tid] = 0.01f / ((pr[2 * tid] + pr[2 * tid + 1]) + EPS_OT);
            __syncthreads();
        }
        // ---- down-sweep: v_j = b_j / (K u) ----
        #pragma unroll
        for (int w = 0; w < WPT; w++) {
            float s = 0.f;
            #pragma unroll
            for (int q = 0; q < 50; q++)
                s += LOBF(ku[w][q]) * u_sh[2 * q] + HIBF(ku[w][q]) * u_sh[2 * q + 1];
            v[w] = bj[w] / (s + EPS_OT);
        }
        if (k == NITER - 1) {
            #pragma unroll
            for (int w = 0; w < WPT; w++) {
                int j = (b * WPT + w) * 256 + tid;
                if (j < V) ws[OFF_VTW + j] = v[w];
            }
        }
        // ---- up-sweep: block partial_t = sum_j K[j][t] v_j -> tagged store ----
        float* Pw = ws + OFF_PART + (size_t)(k & 1) * (T * PSTR);
        unsigned wsign = (unsigned)((k >> 1) & 1) << 31;
        #pragma unroll
        for (int c = 0; c < 4; c++) {
            #pragma unroll
            for (int i = 0; i < 25; i++) {
                int t = 25 * c + i;
                float p = 0.f;
                #pragma unroll
                for (int w = 0; w < WPT; w++) {
                    unsigned wu = ku[w][t >> 1];
                    float kt = (t & 1) ? HIBF(wu) : LOBF(wu);
                    p += kt * v[w];
                }
                sm[tid * 26 + i] = p;
            }
            __syncthreads();
            int g = tid >> 5, tl = tid & 31;
            float s2 = 0.f;
            if (tl < 25) {
                #pragma unroll 8
                for (int q = 0; q < 32; q++) s2 += sm[(g * 32 + q) * 26 + tl];
            }
            pr[g * 32 + tl] = s2;
            __syncthreads();
            if (tid < 25) {
                float r = 0.f;
                #pragma unroll
                for (int g2 = 0; g2 < 8; g2++) r += pr[g2 * 32 + tid];
                stg_coh1(Pw + (25 * c + tid) * PSTR + b,
                         __uint_as_float(__float_as_uint(r) | wsign));
            }
            __syncthreads();   // drains ALL partial stores (vmcnt(0) before s_barrier)
        }
        // ---- publish per-block flag: partials guaranteed visible before this ----
        if (tid == 0)
            stg_coh1(ws + OFF_FLG + (size_t)(k & 1) * 64 + b, __uint_as_float(wsign | 1u));
    }
    // ---- fused TW epilogue: final u from iter-99 partials (flags+bulk) + TW loss ----
    {
        if (tid < NBTW)
            poll_flag(ws + OFF_FLG + (size_t)((NITER - 1) & 1) * 64 + tid, ((NITER - 1) >> 1) & 1);
        __syncthreads();
        float rs = 0.f;
        if (tid < 2 * T) {
            int t = tid >> 1, half = tid & 1;
            const float* Pp = ws + OFF_PART + (size_t)((NITER - 1) & 1) * (T * PSTR)
                              + t * PSTR + half * 20;
            rs = read_sum20(Pp);
        }
        pr[tid] = rs;
        __syncthreads();
        if (tid < T) {
            float uf = 0.01f / ((pr[2 * tid] + pr[2 * tid + 1]) + EPS_OT);
            u_sh[tid] = uf;
            if (b == 0) ws[OFF_UTW + tid] = uf;
        }
        __syncthreads();
    }
    float lt = 0.f;
    #pragma unroll
    for (int w = 0; w < WPT; w++) {
        int j = (b * WPT + w) * 256 + tid;
        if (j < V) {
            #pragma unroll
            for (int q = 0; q < 50; q++) {
                float k0 = LOBF(ku[w][q]), k1 = HIBF(ku[w][q]);
                if (k0 > 0.f) lt += u_sh[2 * q]     * k0 * v[w] * (-0.5f * logf(k0));
                if (k1 > 0.f) lt += u_sh[2 * q + 1] * k1 * v[w] * (-0.5f * logf(k1));
            }
        }
    }
    float ltb = brsum(lt, red8);
    if (tid == 0) atomicAdd((double*)(ws + OFF_DBL) + 2, (double)ltb);
}

// ---------- DSR slow path only (theta != 0 somewhere) ----------
__global__ void k_dsr(const float* __restrict__ bow, float* ws) {
    if (*(volatile int*)(((int*)ws) + OFF_FLAG) == 0) return;
    __shared__ float th[32 * T];
    __shared__ float u2[T];
    __shared__ float vd[T];
    __shared__ float red[256];
    __shared__ int flag;
    int tid = threadIdx.x;
    int j0 = blockIdx.x * 256;
    int d0 = blockIdx.y * 32;
    if (tid < T) { vd[tid] = ws[OFF_VDT + tid]; u2[tid] = ws[OFF_UTW + tid]; }
    if (tid == 0) flag = 0;
    __syncthreads();
    bool nz = false;
    for (int idx = tid; idx < 32 * T; idx += 256) {
        int dl = idx / T; int t = idx - dl * T;
        float thv = (float)N * ws[OFF_UDT + d0 + dl] * ws[OFF_KDT + (size_t)(d0 + dl) * T + t] * vd[t];
        th[idx] = thv;
        nz |= (thv != 0.f);
    }
    if (nz) flag = 1;
    __syncthreads();
    int j = j0 + tid;
    float part = 0.f;
    const unsigned short* kg = (const unsigned short*)(ws + OFF_KTW);
    if (flag) {
        float acc[32];
        #pragma unroll
        for (int d = 0; d < 32; d++) acc[d] = 0.f;
        if (j < V) {
            float vj = ws[OFF_VTW + j];
            for (int t = 0; t < T; t++) {
                float kv = bf2f(kg[(size_t)j * KSTR + t]);
                float beta = (float)T * u2[t] * kv * vj;
                #pragma unroll
                for (int d = 0; d < 32; d++) acc[d] += th[d * T + t] * beta;
            }
            for (int d = 0; d < 32; d++)
                part += bow[(size_t)(d0 + d) * V + j] * logf(acc[d] + EPS_LOG);
        }
    } else {
        if (j < V) {
            float sb = 0.f;
            #pragma unroll 8
            for (int d = 0; d < 32; d++) sb += bow[(size_t)(d0 + d) * V + j];
            part = sb * logf(EPS_LOG);
        }
    }
    red[tid] = part; __syncthreads();
    for (int s = 128; s > 0; s >>= 1) { if (tid < s) red[tid] += red[tid + s]; __syncthreads(); }
    if (tid == 0) atomicAdd((double*)(ws + OFF_DBL) + 0, (double)red[0]);
}

// ---------- combine ----------
__global__ void k_finish(float* ws, float* out) {
    if (threadIdx.x == 0 && blockIdx.x == 0) {
        double* dbl = (double*)(ws + OFF_DBL);
        int flag = ((int*)ws)[OFF_FLAG];
        double dsr_sum = flag ? dbl[0] : dbl[3] * (double)logf(EPS_LOG);
        double ldsr = -dsr_sum / (double)N;
        double letp = dbl[1] + dbl[2];
        out[0] = (float)(ldsr + letp);
        out[1] = (float)ldsr;
        out[2] = (float)letp;
    }
}

extern "C" void kernel_launch(void* const* d_in, const int* in_sizes, int n_in,
                              void* d_out, int out_size, void* d_ws, size_t ws_size,
                              hipStream_t stream) {
    const float* bow  = (const float*)d_in[0];
    const float* de   = (const float*)d_in[1];
    const float* we   = (const float*)d_in[2];
    const float* te   = (const float*)d_in[3];
    const float* wwgt = (const float*)d_in[4];
    const float* twgt = (const float*)d_in[5];
    float* out = (float*)d_out;
    float* ws  = (float*)d_ws;

    k_pre<<<128, 256, 0, stream>>>(we, de, te, wwgt, twgt, ws);
    k_pre2<<<118, 256, 0, stream>>>(wwgt, ws);
    k_ktw<<<dim3(118, 4), 256, 0, stream>>>(we, te, ws);
    k_kdt<<<800, 256, 0, stream>>>(de, te, ws);
    // persistent dispatch: 40 TW + 128 bow + 8 DT = 176 blocks <= 256 CUs.
    k_sink<<<NBTW + 128 + NDT, 256, 0, stream>>>(bow, ws);
    k_dsr<<<dim3(118, 64), 256, 0, stream>>>(bow, ws);
    k_finish<<<1, 64, 0, stream>>>(ws, out);
}

// Round 10
// 1274.476 us; speedup vs baseline: 1.0691x; 1.0691x over previous
//
#include <hip/hip_runtime.h>
#include <math.h>

#define V 30000
#define E 200
#define T 100
#define N 2048
#define NITER 100
#define KSTR 112          // padded K_TW row stride in ushorts (224 B, 16B-aligned)
#define EPS_OT 1e-16f
#define EPS_LOG 1e-12f

#define NBTW 40           // TW sinkhorn blocks
#define WPT 3             // K rows (words) per thread: 40*256*3 = 30720 >= V
#define NDT 8             // DT blocks (gated)
#define PSTR 64           // per-topic partial stride (floats): 40 used, 64 padded

// ws float offsets
#define OFF_KTW    0            // ushort[V*KSTR] bf16 word-major = 1,680,000 floats
#define OFF_KDT    1680000      // float[N*T]
#define OFF_WW     1884800      // V
#define OFF_DD     1914800      // N
#define OFF_TT     1916848      // 128
#define OFF_PM     1916976      // 128
#define OFF_PS     1917104      // 128
#define OFF_BTW    1917232      // V    softmax(word_weights)
#define OFF_BDT    1947232      // 128  softmax(topic_weights)
#define OFF_ACC    1947360      // NITER*T (legacy, still zeroed)
#define OFF_ACCDT  1957360      // NITER*T DT accumulators (gated)
#define OFF_VTW    1967360      // V
#define OFF_UDT    1997360      // N
#define OFF_UTW    1999408      // 128
#define OFF_VDT    1999536      // 128
#define OFF_DBL    1999664      // 16 floats = 8 doubles
#define OFF_FLAG   1999680      // int index: theta nonzero
#define OFF_KDTNZ  1999681      // int index: any K_DT nonzero
#define OFF_ARR    1999682      // int[2*NITER]: DT arrive counters
#define OFF_PART   2000000      // float[2][T][PSTR] double-buffered TW partials, topic-major
                                // sign bit of each value = iteration tag (k>>1)&1
#define OFF_UARR   2013000      // float[2][128] double-buffered tagged u vectors
                                // u for consume-iter k at buf[k&1], tag (k>>1)&1

#define LOBF(u) __uint_as_float((u) << 16)
#define HIBF(u) __uint_as_float((u) & 0xffff0000u)

typedef __attribute__((ext_vector_type(4))) float f32x4;

__device__ __forceinline__ unsigned short f2bf(float f) {
    unsigned int u = __float_as_uint(f);
    return (unsigned short)((u + 0x7fffu + ((u >> 16) & 1u)) >> 16);
}
__device__ __forceinline__ float bf2f(unsigned short h) {
    return __uint_as_float(((unsigned int)h) << 16);
}

__device__ __forceinline__ float brsum(float x, float* red8) {
    int tid = threadIdx.x;
    for (int o = 32; o; o >>= 1) x += __shfl_down(x, o, 64);
    __syncthreads();
    if ((tid & 63) == 0) red8[tid >> 6] = x;
    __syncthreads();
    return (red8[0] + red8[1]) + (red8[2] + red8[3]);
}

__device__ __forceinline__ void load_krow(const unsigned short* kg, int j, unsigned* ku) {
    const uint4* kp = (const uint4*)(kg + (size_t)j * KSTR);
    #pragma unroll
    for (int i = 0; i < 12; i++) {
        uint4 q = kp[i];
        ku[4*i] = q.x; ku[4*i+1] = q.y; ku[4*i+2] = q.z; ku[4*i+3] = q.w;
    }
    uint2 q2 = *(const uint2*)(((const unsigned*)kp) + 48);
    ku[48] = q2.x; ku[49] = q2.y;
}

// coherent (L1/L2-bypassing) memory ops: L3 is the cross-XCD coherence point.
__device__ __forceinline__ f32x4 ldg_coh4(const float* p) {
    f32x4 r;
    asm volatile("global_load_dwordx4 %0, %1, off sc0 sc1" : "=v"(r) : "v"(p) : "memory");
    return r;
}
__device__ __forceinline__ void stg_coh1(float* p, float v) {
    asm volatile("global_store_dword %0, %1, off sc0 sc1" :: "v"(p), "v"(v) : "memory");
}
__device__ __forceinline__ void stg_coh4(float* p, f32x4 v) {
    asm volatile("global_store_dwordx4 %0, %1, off sc0 sc1" :: "v"(p), "v"(v) : "memory");
}
__device__ __forceinline__ void wait_vm0() {
    asm volatile("s_waitcnt vmcnt(0)" ::: "memory");
    __builtin_amdgcn_sched_barrier(0);
}

// Poll 20 tagged partials (5 dwordx4) until every sign bit == ptag, then return
// the magnitude sum (fixed tree, bit-identical to R4/R5/R8).
__device__ __forceinline__ float poll_sum20(const float* Pp, unsigned ptag) {
    f32x4 a0, a1, a2, a3, a4;
    while (true) {
        a0 = ldg_coh4(Pp + 0);
        a1 = ldg_coh4(Pp + 4);
        a2 = ldg_coh4(Pp + 8);
        a3 = ldg_coh4(Pp + 12);
        a4 = ldg_coh4(Pp + 16);
        wait_vm0();
        unsigned u0x = __float_as_uint(a0.x), u0y = __float_as_uint(a0.y),
                 u0z = __float_as_uint(a0.z), u0w = __float_as_uint(a0.w);
        unsigned u1x = __float_as_uint(a1.x), u1y = __float_as_uint(a1.y),
                 u1z = __float_as_uint(a1.z), u1w = __float_as_uint(a1.w);
        unsigned u2x = __float_as_uint(a2.x), u2y = __float_as_uint(a2.y),
                 u2z = __float_as_uint(a2.z), u2w = __float_as_uint(a2.w);
        unsigned u3x = __float_as_uint(a3.x), u3y = __float_as_uint(a3.y),
                 u3z = __float_as_uint(a3.z), u3w = __float_as_uint(a3.w);
        unsigned u4x = __float_as_uint(a4.x), u4y = __float_as_uint(a4.y),
                 u4z = __float_as_uint(a4.z), u4w = __float_as_uint(a4.w);
        unsigned and_ = u0x & u0y & u0z & u0w & u1x & u1y & u1z & u1w
                      & u2x & u2y & u2z & u2w & u3x & u3y & u3z & u3w
                      & u4x & u4y & u4z & u4w;
        unsigned or_  = u0x | u0y | u0z | u0w | u1x | u1y | u1z | u1w
                      | u2x | u2y | u2z | u2w | u3x | u3y | u3z | u3w
                      | u4x | u4y | u4z | u4w;
        if (ptag ? (and_ >> 31) : !(or_ >> 31)) break;
        __builtin_amdgcn_s_sleep(1);
    }
    return (((fabsf(a0.x) + fabsf(a0.y)) + (fabsf(a0.z) + fabsf(a0.w)))
          + ((fabsf(a1.x) + fabsf(a1.y)) + (fabsf(a1.z) + fabsf(a1.w))))
         + (((fabsf(a2.x) + fabsf(a2.y)) + (fabsf(a2.z) + fabsf(a2.w)))
          + ((fabsf(a3.x) + fabsf(a3.y)) + (fabsf(a3.z) + fabsf(a3.w))))
         + ((fabsf(a4.x) + fabsf(a4.y)) + (fabsf(a4.z) + fabsf(a4.w)));
}

// Poll one dwordx4 of tagged u values until all 4 sign bits == ptag (no sleep).
__device__ __forceinline__ f32x4 poll_u4(const float* p, unsigned ptag) {
    f32x4 a;
    while (true) {
        a = ldg_coh4(p);
        wait_vm0();
        unsigned ax = __float_as_uint(a.x), ay = __float_as_uint(a.y),
                 az = __float_as_uint(a.z), aw = __float_as_uint(a.w);
        unsigned and_ = ax & ay & az & aw;
        unsigned or_  = ax | ay | az | aw;
        if (ptag ? (and_ >> 31) : !(or_ >> 31)) break;
    }
    return a;
}

// legacy counter barrier (DT role only, 8 blocks)
__device__ __forceinline__ void gbar(int* ctr, int n, int tid) {
    __syncthreads();
    if (tid == 0) {
        __hip_atomic_fetch_add(ctr, 1, __ATOMIC_RELEASE, __HIP_MEMORY_SCOPE_AGENT);
        while (__hip_atomic_load(ctr, __ATOMIC_ACQUIRE, __HIP_MEMORY_SCOPE_AGENT) < n)
            __builtin_amdgcn_s_sleep(1);
    }
    __syncthreads();
}

__device__ __forceinline__ float agent_ldf(const float* p) {
    return __hip_atomic_load(p, __ATOMIC_RELAXED, __HIP_MEMORY_SCOPE_AGENT);
}

// ---------- zeroing + row norms + word-softmax partials + topic softmax ----------
__global__ void k_pre(const float* __restrict__ we, const float* __restrict__ de,
                      const float* __restrict__ te, const float* __restrict__ wwgt,
                      const float* __restrict__ twgt, float* ws) {
    __shared__ float red[256];
    int tid = threadIdx.x, b = blockIdx.x;
    int gid = b * 256 + tid;
    if (gid < 2 * NITER * T) ws[OFF_ACC + gid] = 0.f;      // ACC + ACCDT contiguous
    if (gid < 16) ws[OFF_DBL + gid] = 0.f;
    if (gid < 2) ((int*)ws)[OFF_FLAG + gid] = 0;
    if (gid < 2 * NITER) ((int*)ws)[OFF_ARR + gid] = 0;    // DT barrier counters
    if (gid < 2 * T * PSTR) ws[OFF_PART + gid] = __uint_as_float(0x80000000u); // tag=1 preset
    if (gid < 256) ws[OFF_UARR + gid] = (gid < 128) ? 0.f : __uint_as_float(0x80000000u);
    {   // squared row norms
        int r = gid;
        const float* src = nullptr; float* dst = nullptr; int row = 0;
        if (r < V)              { src = we; dst = ws + OFF_WW; row = r; }
        else if (r < V + N)     { src = de; dst = ws + OFF_DD; row = r - V; }
        else if (r < V + N + T) { src = te; dst = ws + OFF_TT; row = r - V - N; }
        if (src) {
            const float4* p = (const float4*)(src + (size_t)row * E);
            float s = 0.f;
            #pragma unroll 10
            for (int i = 0; i < E / 4; i++) { float4 v = p[i]; s += v.x*v.x + v.y*v.y + v.z*v.z + v.w*v.w; }
            dst[row] = s;
        }
    }
    if (b < 118) {  // word-softmax partials
        int j = gid;
        float w = (j < V) ? wwgt[j] : -INFINITY;
        red[tid] = w; __syncthreads();
        for (int s = 128; s > 0; s >>= 1) { if (tid < s) red[tid] = fmaxf(red[tid], red[tid + s]); __syncthreads(); }
        float m = red[0]; __syncthreads();
        float e = (j < V) ? expf(w - m) : 0.f;
        red[tid] = e; __syncthreads();
        for (int s = 128; s > 0; s >>= 1) { if (tid < s) red[tid] += red[tid + s]; __syncthreads(); }
        if (tid == 0) { ws[OFF_PM + b] = m; ws[OFF_PS + b] = red[0]; }
    } else if (b == 120) {  // topic softmax -> b_dt
        float w = (tid < T) ? twgt[tid] : -INFINITY;
        red[tid] = w; __syncthreads();
        for (int s = 128; s > 0; s >>= 1) { if (tid < s) red[tid] = fmaxf(red[tid], red[tid + s]); __syncthreads(); }
        float m = red[0]; __syncthreads();
        float e = (tid < T) ? expf(w - m) : 0.f;
        red[tid] = e; __syncthreads();
        for (int s = 128; s > 0; s >>= 1) { if (tid < s) red[tid] += red[tid + s]; __syncthreads(); }
        if (tid < T) ws[OFF_BDT + tid] = e / red[0];
    }
}

// ---------- merge word-softmax partials -> b_tw ----------
__global__ void k_pre2(const float* __restrict__ wwgt, float* ws) {
    __shared__ float red[128];
    int tid = threadIdx.x, b = blockIdx.x;
    float m = (tid < 118) ? ws[OFF_PM + tid] : -INFINITY;
    if (tid < 128) red[tid] = m;
    __syncthreads();
    for (int s = 64; s > 0; s >>= 1) { if (tid < s) red[tid] = fmaxf(red[tid], red[tid + s]); __syncthreads(); }
    float mw = red[0]; __syncthreads();
    float p = (tid < 118) ? ws[OFF_PS + tid] * expf(ws[OFF_PM + tid] - mw) : 0.f;
    if (tid < 128) red[tid] = p;
    __syncthreads();
    for (int s = 64; s > 0; s >>= 1) { if (tid < s) red[tid] += red[tid + s]; __syncthreads(); }
    float Sw = red[0];
    int j = b * 256 + tid;
    if (j < V) ws[OFF_BTW + j] = expf(wwgt[j] - mw) / Sw;
}

// ---------- K_TW[j][t] = bf16(exp(-2*sqdist)), word-major stride KSTR ----------
__global__ void k_ktw(const float* __restrict__ we, const float* __restrict__ te, float* ws) {
    __shared__ float wt[8][256];
    __shared__ float tp[8][25];
    __shared__ float tts[25];
    int tid = threadIdx.x;
    int j0 = blockIdx.x * 256;
    int t0 = blockIdx.y * 25;
    int j = j0 + tid;
    int jl = (j < V) ? j : V - 1;
    float acc[25];
    #pragma unroll
    for (int i = 0; i < 25; i++) acc[i] = 0.f;
    if (tid < 25) tts[tid] = ws[OFF_TT + t0 + tid];
    for (int kk = 0; kk < E; kk += 8) {
        #pragma unroll
        for (int k = 0; k < 8; k++) wt[k][tid] = we[(size_t)jl * E + kk + k];
        if (tid < 200) { int i = tid >> 3; int k = tid & 7; tp[k][i] = te[(size_t)(t0 + i) * E + kk + k]; }
        __syncthreads();
        #pragma unroll
        for (int k = 0; k < 8; k++) {
            float w = wt[k][tid];
            #pragma unroll
            for (int i = 0; i < 25; i++) acc[i] += tp[k][i] * w;
        }
        __syncthreads();
    }
    if (j < V) {
        float wwj = ws[OFF_WW + j];
        unsigned short* kg = (unsigned short*)(ws + OFF_KTW);
        #pragma unroll
        for (int i = 0; i < 25; i++) {
            float M = tts[i] + wwj - 2.f * acc[i];
            kg[(size_t)j * KSTR + t0 + i] = f2bf(expf(-2.f * M));
        }
    }
}

// ---------- K_DT[n][t] = exp(-3*sqdist), fp32, + any-nonzero flag ----------
__global__ void k_kdt(const float* __restrict__ de, const float* __restrict__ te, float* ws) {
    int gid = blockIdx.x * 256 + threadIdx.x;
    if (gid >= N * T) return;
    int n = gid / T; int t = gid - n * T;
    const float4* dp  = (const float4*)(de + (size_t)n * E);
    const float4* tpp = (const float4*)(te + (size_t)t * E);
    float s = 0.f;
    #pragma unroll 10
    for (int i = 0; i < E / 4; i++) { float4 a = dp[i], b = tpp[i]; s += a.x*b.x + a.y*b.y + a.z*b.z + a.w*b.w; }
    float M = ws[OFF_DD + n] + ws[OFF_TT + t] - 2.f * s;
    float kv = expf(-3.f * M);
    ws[OFF_KDT + gid] = kv;
    unsigned long long m = __ballot(kv != 0.f);
    if (m && (threadIdx.x & 63) == 0) atomicOr(((int*)ws) + OFF_KDTNZ, 1);
}

// ---------- persistent fused sinkhorn (R5 topology + drain-free producers) ----------
// blocks 0..NBTW-1      : TW sinkhorn, WPT=3 K-rows/thread in registers.
//   per iter: poll tagged u (25 thr x dwordx4), down-sweep, up-sweep with chunk
//   results stashed in registers, then ALL 4 tagged stores issued at once with NO
//   trailing barrier (tagged words are self-validating; stores complete
//   autonomously; no forced vmcnt(0) drains on the critical path).
// blocks NBTW..NBTW+127 : bow total sum (free-running, bit-identical chunking)
// blocks NBTW+128..+135 : DT sinkhorn (gated on kdtnz) + fused DT epilogue
// block  NBTW+128+NDT   : u-reducer: polls 40x100 tagged partials, publishes tagged u.
__global__ __launch_bounds__(256, 1) void k_sink(const float* __restrict__ bow, float* ws) {
    __shared__ float sm[256 * 26];
    __shared__ float pr[256];
    __shared__ float u_sh[100];
    __shared__ float red8[8];
    int tid = threadIdx.x, b = blockIdx.x;

    if (b >= NBTW && b < NBTW + 128) {    // ---- bow role ----
        const float4* b4 = (const float4*)bow;
        for (int k = 0; k < 96; k++) {
            size_t base = (size_t)k * 160000;
            float s = 0.f;
            for (int i = (b - NBTW) * 256 + tid; i < 160000; i += 128 * 256) {
                float4 x = b4[base + i]; s += (x.x + x.y) + (x.z + x.w);
            }
            float bs = brsum(s, red8);
            if (tid == 0) atomicAdd((double*)(ws + OFF_DBL) + 3, (double)bs);
        }
        return;
    }

    if (b >= NBTW + 128 && b < NBTW + 128 + NDT) {   // ---- DT role (gated) ----
        if (((volatile int*)ws)[OFF_KDTNZ] == 0) return;
        int* arr = ((int*)ws) + OFF_ARR;
        int d = (b - (NBTW + 128)) * 256 + tid;    // 0..2047
        const float* Kr = ws + OFF_KDT + (size_t)d * T;
        for (int k = 0; k < NITER; k++) {
            if (tid < T) u_sh[tid] = (k == 0) ? 0.f
                : ws[OFF_BDT + tid] / (agent_ldf(ws + OFF_ACCDT + (k - 1) * T + tid) + EPS_OT);
            __syncthreads();
            float u;
            if (k == 0) u = 1.f / N;
            else {
                float s = 0.f;
                #pragma unroll 4
                for (int t = 0; t < T; t++) s += Kr[t] * u_sh[t];
                u = (1.f / N) / (s + EPS_OT);
            }
            #pragma unroll
            for (int c = 0; c < 4; c++) {
                #pragma unroll
                for (int i = 0; i < 25; i++) sm[tid * 26 + i] = Kr[25 * c + i] * u;
                __syncthreads();
                int g = tid >> 5, tl = tid & 31;
                float s2 = 0.f;
                if (tl < 25) {
                    #pragma unroll 8
                    for (int q = 0; q < 32; q++) s2 += sm[(g * 32 + q) * 26 + tl];
                }
                pr[g * 32 + tl] = s2;
                __syncthreads();
                if (tid < 25) {
                    float r = 0.f;
                    #pragma unroll
                    for (int g2 = 0; g2 < 8; g2++) r += pr[g2 * 32 + tid];
                    atomicAdd(&ws[OFF_ACCDT + k * T + 25 * c + tid], r);
                }
                __syncthreads();
            }
            gbar(arr + NITER + k, NDT, tid);
        }
        if (tid < T) {
            float vf = ws[OFF_BDT + tid] / (agent_ldf(ws + OFF_ACCDT + (NITER - 1) * T + tid) + EPS_OT);
            u_sh[tid] = vf;
            if (b == NBTW + 128) ws[OFF_VDT + tid] = vf;
        }
        __syncthreads();
        float s = 0.f;
        #pragma unroll 4
        for (int t = 0; t < T; t++) s += Kr[t] * u_sh[t];
        float u = (1.f / N) / (s + EPS_OT);
        ws[OFF_UDT + d] = u;
        float ld = 0.f; int nz = 0;
        for (int t = 0; t < T; t++) {
            float kv = Kr[t];
            if (kv > 0.f) ld += u * kv * u_sh[t] * (-(1.f / 3.f) * logf(kv));
            if ((float)N * u * kv * u_sh[t] != 0.f) nz = 1;
        }
        float ldb = brsum(ld, red8);
        if (tid == 0) atomicAdd((double*)(ws + OFF_DBL) + 1, (double)ldb);
        if (nz) atomicOr(((int*)ws) + OFF_FLAG, 1);
        return;
    }

    if (b >= NBTW + 128 + NDT) {          // ---- u-reducer block ----
        for (int k = 1; k <= NITER; k++) {
            float rs = 0.f;
            if (tid < 2 * T) {
                int t = tid >> 1, half = tid & 1;
                const float* Pp = ws + OFF_PART + (size_t)((k - 1) & 1) * (T * PSTR)
                                  + t * PSTR + half * 20;
                rs = poll_sum20(Pp, ((k - 1) >> 1) & 1);
            }
            pr[tid] = rs;
            __syncthreads();
            if (tid < T) u_sh[tid] = 0.01f / ((pr[2 * tid] + pr[2 * tid + 1]) + EPS_OT);
            __syncthreads();
            unsigned usign = (unsigned)((k >> 1) & 1) << 31;
            if (tid < 25) {
                f32x4 uv;
                uv.x = __uint_as_float(__float_as_uint(u_sh[4 * tid + 0]) | usign);
                uv.y = __uint_as_float(__float_as_uint(u_sh[4 * tid + 1]) | usign);
                uv.z = __uint_as_float(__float_as_uint(u_sh[4 * tid + 2]) | usign);
                uv.w = __uint_as_float(__float_as_uint(u_sh[4 * tid + 3]) | usign);
                stg_coh4(ws + OFF_UARR + (size_t)(k & 1) * 128 + 4 * tid, uv);
            }
            __syncthreads();
        }
        return;
    }

    // ---- TW role ----
    const unsigned short* kg = (const unsigned short*)(ws + OFF_KTW);
    unsigned ku[WPT][50];
    float bj[WPT];
    #pragma unroll
    for (int w = 0; w < WPT; w++) {
        int j = (b * WPT + w) * 256 + tid;
        bool oob = (j >= V);
        load_krow(kg, oob ? V - 1 : j, ku[w]);
        if (oob) {
            #pragma unroll
            for (int q = 0; q < 50; q++) ku[w][q] = 0;
        }
        bj[w] = oob ? 0.f : ws[OFF_BTW + j];
    }
    float v[WPT];
    #pragma unroll
    for (int w = 0; w < WPT; w++) v[w] = 0.f;

    for (int k = 0; k < NITER; k++) {
        // ---- u for iter k: poll tagged u vector from reducer (25 threads) ----
        if (k == 0) {
            if (tid < T) u_sh[tid] = 0.01f;
        } else if (tid < 25) {
            f32x4 a = poll_u4(ws + OFF_UARR + (size_t)(k & 1) * 128 + 4 * tid, (k >> 1) & 1);
            u_sh[4 * tid + 0] = fabsf(a.x);
            u_sh[4 * tid + 1] = fabsf(a.y);
            u_sh[4 * tid + 2] = fabsf(a.z);
            u_sh[4 * tid + 3] = fabsf(a.w);
        }
        __syncthreads();
        // ---- down-sweep: v_j = b_j / (K u) ----
        #pragma unroll
        for (int w = 0; w < WPT; w++) {
            float s = 0.f;
            #pragma unroll
            for (int q = 0; q < 50; q++)
                s += LOBF(ku[w][q]) * u_sh[2 * q] + HIBF(ku[w][q]) * u_sh[2 * q + 1];
            v[w] = bj[w] / (s + EPS_OT);
        }
        if (k == NITER - 1) {
            #pragma unroll
            for (int w = 0; w < WPT; w++) {
                int j = (b * WPT + w) * 256 + tid;
                if (j < V) ws[OFF_VTW + j] = v[w];
            }
        }
        // ---- up-sweep: 4 chunks, 2 barriers each, results stashed in registers ----
        float rc0 = 0.f, rc1 = 0.f, rc2 = 0.f, rc3 = 0.f;
        #pragma unroll
        for (int c = 0; c < 4; c++) {
            #pragma unroll
            for (int i = 0; i < 25; i++) {
                int t = 25 * c + i;
                float p = 0.f;
                #pragma unroll
                for (int w = 0; w < WPT; w++) {
                    unsigned wu = ku[w][t >> 1];
                    float kt = (t & 1) ? HIBF(wu) : LOBF(wu);
                    p += kt * v[w];
                }
                sm[tid * 26 + i] = p;
            }
            __syncthreads();
            int g = tid >> 5, tl = tid & 31;
            float s2 = 0.f;
            if (tl < 25) {
                #pragma unroll 8
                for (int q = 0; q < 32; q++) s2 += sm[(g * 32 + q) * 26 + tl];
            }
            pr[g * 32 + tl] = s2;
            __syncthreads();
            if (tid < 25) {
                float r = 0.f;
                #pragma unroll
                for (int g2 = 0; g2 < 8; g2++) r += pr[g2 * 32 + tid];
                if (c == 0) rc0 = r; else if (c == 1) rc1 = r;
                else if (c == 2) rc2 = r; else rc3 = r;
            }
            // no trailing barrier: next chunk's sm writes don't conflict with pr
            // reads (different arrays; pr rewrite is fenced by next chunk's barrier)
        }
        // ---- issue ALL tagged stores at once; NO drain (self-validating words) ----
        if (tid < 25) {
            float* Pw = ws + OFF_PART + (size_t)(k & 1) * (T * PSTR);
            unsigned wsign = (unsigned)((k >> 1) & 1) << 31;
            stg_coh1(Pw + (25 * 0 + tid) * PSTR + b, __uint_as_float(__float_as_uint(rc0) | wsign));
            stg_coh1(Pw + (25 * 1 + tid) * PSTR + b, __uint_as_float(__float_as_uint(rc1) | wsign));
            stg_coh1(Pw + (25 * 2 + tid) * PSTR + b, __uint_as_float(__float_as_uint(rc2) | wsign));
            stg_coh1(Pw + (25 * 3 + tid) * PSTR + b, __uint_as_float(__float_as_uint(rc3) | wsign));
        }
        // loop back: next iteration's u-poll gates progress; stores complete in flight
    }
    // ---- fused TW epilogue: final u = iter-100 u from reducer + TW loss ----
    if (tid < 25) {
        f32x4 a = poll_u4(ws + OFF_UARR + (size_t)(NITER & 1) * 128 + 4 * tid, (NITER >> 1) & 1);
        u_sh[4 * tid + 0] = fabsf(a.x);
        u_sh[4 * tid + 1] = fabsf(a.y);
        u_sh[4 * tid + 2] = fabsf(a.z);
        u_sh[4 * tid + 3] = fabsf(a.w);
    }
    __syncthreads();
    if (b == 0 && tid < T) ws[OFF_UTW + tid] = u_sh[tid];
    float lt = 0.f;
    #pragma unroll
    for (int w = 0; w < WPT; w++) {
        int j = (b * WPT + w) * 256 + tid;
        if (j < V) {
            #pragma unroll
            for (int q = 0; q < 50; q++) {
                float k0 = LOBF(ku[w][q]), k1 = HIBF(ku[w][q]);
                if (k0 > 0.f) lt += u_sh[2 * q]     * k0 * v[w] * (-0.5f * logf(k0));
                if (k1 > 0.f) lt += u_sh[2 * q + 1] * k1 * v[w] * (-0.5f * logf(k1));
            }
        }
    }
    float ltb = brsum(lt, red8);
    if (tid == 0) atomicAdd((double*)(ws + OFF_DBL) + 2, (double)ltb);
}

// ---------- DSR slow path only (theta != 0 somewhere) ----------
__global__ void k_dsr(const float* __restrict__ bow, float* ws) {
    if (*(volatile int*)(((int*)ws) + OFF_FLAG) == 0) return;
    __shared__ float th[32 * T];
    __shared__ float u2[T];
    __shared__ float vd[T];
    __shared__ float red[256];
    __shared__ int flag;
    int tid = threadIdx.x;
    int j0 = blockIdx.x * 256;
    int d0 = blockIdx.y * 32;
    if (tid < T) { vd[tid] = ws[OFF_VDT + tid]; u2[tid] = ws[OFF_UTW + tid]; }
    if (tid == 0) flag = 0;
    __syncthreads();
    bool nz = false;
    for (int idx = tid; idx < 32 * T; idx += 256) {
        int dl = idx / T; int t = idx - dl * T;
        float thv = (float)N * ws[OFF_UDT + d0 + dl] * ws[OFF_KDT + (size_t)(d0 + dl) * T + t] * vd[t];
        th[idx] = thv;
        nz |= (thv != 0.f);
    }
    if (nz) flag = 1;
    __syncthreads();
    int j = j0 + tid;
    float part = 0.f;
    const unsigned short* kg = (const unsigned short*)(ws + OFF_KTW);
    if (flag) {
        float acc[32];
        #pragma unroll
        for (int d = 0; d < 32; d++) acc[d] = 0.f;
        if (j < V) {
            float vj = ws[OFF_VTW + j];
            for (int t = 0; t < T; t++) {
                float kv = bf2f(kg[(size_t)j * KSTR + t]);
                float beta = (float)T * u2[t] * kv * vj;
                #pragma unroll
                for (int d = 0; d < 32; d++) acc[d] += th[d * T + t] * beta;
            }
            for (int d = 0; d < 32; d++)
                part += bow[(size_t)(d0 + d) * V + j] * logf(acc[d] + EPS_LOG);
        }
    } else {
        if (j < V) {
            float sb = 0.f;
            #pragma unroll 8
            for (int d = 0; d < 32; d++) sb += bow[(size_t)(d0 + d) * V + j];
            part = sb * logf(EPS_LOG);
        }
    }
    red[tid] = part; __syncthreads();
    for (int s = 128; s > 0; s >>= 1) { if (tid < s) red[tid] += red[tid + s]; __syncthreads(); }
    if (tid == 0) atomicAdd((double*)(ws + OFF_DBL) + 0, (double)red[0]);
}

// ---------- combine ----------
__global__ void k_finish(float* ws, float* out) {
    if (threadIdx.x == 0 && blockIdx.x == 0) {
        double* dbl = (double*)(ws + OFF_DBL);
        int flag = ((int*)ws)[OFF_FLAG];
        double dsr_sum = flag ? dbl[0] : dbl[3] * (double)logf(EPS_LOG);
        double ldsr = -dsr_sum / (double)N;
        double letp = dbl[1] + dbl[2];
        out[0] = (float)(ldsr + letp);
        out[1] = (float)ldsr;
        out[2] = (float)letp;
    }
}

extern "C" void kernel_launch(void* const* d_in, const int* in_sizes, int n_in,
                              void* d_out, int out_size, void* d_ws, size_t ws_size,
                              hipStream_t stream) {
    const float* bow  = (const float*)d_in[0];
    const float* de   = (const float*)d_in[1];
    const float* we   = (const float*)d_in[2];
    const float* te   = (const float*)d_in[3];
    const float* wwgt = (const float*)d_in[4];
    const float* twgt = (const float*)d_in[5];
    float* out = (float*)d_out;
    float* ws  = (float*)d_ws;

    k_pre<<<128, 256, 0, stream>>>(we, de, te, wwgt, twgt, ws);
    k_pre2<<<118, 256, 0, stream>>>(wwgt, ws);
    k_ktw<<<dim3(118, 4), 256, 0, stream>>>(we, te, ws);
    k_kdt<<<800, 256, 0, stream>>>(de, te, ws);
    // persistent dispatch: 40 TW + 128 bow + 8 DT + 1 reducer = 177 <= 256 CUs.
    k_sink<<<NBTW + 128 + NDT + 1, 256, 0, stream>>>(bow, ws);
    k_dsr<<<dim3(118, 64), 256, 0, stream>>>(bow, ws);
    k_finish<<<1, 64, 0, stream>>>(ws, out);
}

// Round 11
// 1210.482 us; speedup vs baseline: 1.1256x; 1.0529x over previous
//
#include <hip/hip_runtime.h>
#include <math.h>

#define V 30000
#define E 200
#define T 100
#define N 2048
#define NITER 100
#define KSTR 112          // padded K_TW row stride in ushorts (224 B, 16B-aligned)
#define EPS_OT 1e-16f
#define EPS_LOG 1e-12f

#define NBTW 40           // TW sinkhorn blocks
#define WPT 3             // K rows (words) per thread: 40*256*3 = 30720 >= V
#define NDT 8             // DT blocks (gated)
#define PSTR 64           // per-topic partial stride (floats): 40 used, 64 padded

// ws float offsets
#define OFF_KTW    0            // ushort[V*KSTR] bf16 word-major = 1,680,000 floats
#define OFF_KDT    1680000      // float[N*T]
#define OFF_WW     1884800      // V
#define OFF_DD     1914800      // N
#define OFF_TT     1916848      // 128
#define OFF_PM     1916976      // 128
#define OFF_PS     1917104      // 128
#define OFF_BTW    1917232      // V    softmax(word_weights)
#define OFF_BDT    1947232      // 128  softmax(topic_weights)
#define OFF_ACC    1947360      // NITER*T (legacy, still zeroed)
#define OFF_ACCDT  1957360      // NITER*T DT accumulators (gated)
#define OFF_VTW    1967360      // V
#define OFF_UDT    1997360      // N
#define OFF_UTW    1999408      // 128
#define OFF_VDT    1999536      // 128
#define OFF_DBL    1999664      // 16 floats = 8 doubles
#define OFF_FLAG   1999680      // int index: theta nonzero
#define OFF_KDTNZ  1999681      // int index: any K_DT nonzero
#define OFF_ARR    1999682      // int[2*NITER]: DT arrive counters
#define OFF_PART   2000000      // float[2][T][PSTR] double-buffered TW partials, topic-major
                                // sign bit of each value = iteration tag (k>>1)&1
#define OFF_UARR   2013000      // float[2][128] double-buffered tagged u vectors
                                // u for consume-iter k at buf[k&1], tag (k>>1)&1

#define LOBF(u) __uint_as_float((u) << 16)
#define HIBF(u) __uint_as_float((u) & 0xffff0000u)

typedef __attribute__((ext_vector_type(4))) float f32x4;

__device__ __forceinline__ unsigned short f2bf(float f) {
    unsigned int u = __float_as_uint(f);
    return (unsigned short)((u + 0x7fffu + ((u >> 16) & 1u)) >> 16);
}
__device__ __forceinline__ float bf2f(unsigned short h) {
    return __uint_as_float(((unsigned int)h) << 16);
}

__device__ __forceinline__ float brsum(float x, float* red8) {
    int tid = threadIdx.x;
    for (int o = 32; o; o >>= 1) x += __shfl_down(x, o, 64);
    __syncthreads();
    if ((tid & 63) == 0) red8[tid >> 6] = x;
    __syncthreads();
    return (red8[0] + red8[1]) + (red8[2] + red8[3]);
}

__device__ __forceinline__ void load_krow(const unsigned short* kg, int j, unsigned* ku) {
    const uint4* kp = (const uint4*)(kg + (size_t)j * KSTR);
    #pragma unroll
    for (int i = 0; i < 12; i++) {
        uint4 q = kp[i];
        ku[4*i] = q.x; ku[4*i+1] = q.y; ku[4*i+2] = q.z; ku[4*i+3] = q.w;
    }
    uint2 q2 = *(const uint2*)(((const unsigned*)kp) + 48);
    ku[48] = q2.x; ku[49] = q2.y;
}

// coherent (L1/L2-bypassing) memory ops: L3 is the cross-XCD coherence point.
__device__ __forceinline__ f32x4 ldg_coh4(const float* p) {
    f32x4 r;
    asm volatile("global_load_dwordx4 %0, %1, off sc0 sc1" : "=v"(r) : "v"(p) : "memory");
    return r;
}
__device__ __forceinline__ void stg_coh1(float* p, float v) {
    asm volatile("global_store_dword %0, %1, off sc0 sc1" :: "v"(p), "v"(v) : "memory");
}
__device__ __forceinline__ void stg_coh4(float* p, f32x4 v) {
    asm volatile("global_store_dwordx4 %0, %1, off sc0 sc1" :: "v"(p), "v"(v) : "memory");
}
__device__ __forceinline__ void wait_vm0() {
    asm volatile("s_waitcnt vmcnt(0)" ::: "memory");
    __builtin_amdgcn_sched_barrier(0);
}

// Poll 20 tagged partials (5 dwordx4) until every sign bit == ptag, then return
// the magnitude sum with the SAME summation tree as before (bit-identical).
__device__ __forceinline__ float poll_sum20(const float* Pp, unsigned ptag) {
    f32x4 a0, a1, a2, a3, a4;
    while (true) {
        a0 = ldg_coh4(Pp + 0);
        a1 = ldg_coh4(Pp + 4);
        a2 = ldg_coh4(Pp + 8);
        a3 = ldg_coh4(Pp + 12);
        a4 = ldg_coh4(Pp + 16);
        wait_vm0();
        unsigned u0x = __float_as_uint(a0.x), u0y = __float_as_uint(a0.y),
                 u0z = __float_as_uint(a0.z), u0w = __float_as_uint(a0.w);
        unsigned u1x = __float_as_uint(a1.x), u1y = __float_as_uint(a1.y),
                 u1z = __float_as_uint(a1.z), u1w = __float_as_uint(a1.w);
        unsigned u2x = __float_as_uint(a2.x), u2y = __float_as_uint(a2.y),
                 u2z = __float_as_uint(a2.z), u2w = __float_as_uint(a2.w);
        unsigned u3x = __float_as_uint(a3.x), u3y = __float_as_uint(a3.y),
                 u3z = __float_as_uint(a3.z), u3w = __float_as_uint(a3.w);
        unsigned u4x = __float_as_uint(a4.x), u4y = __float_as_uint(a4.y),
                 u4z = __float_as_uint(a4.z), u4w = __float_as_uint(a4.w);
        unsigned and_ = u0x & u0y & u0z & u0w & u1x & u1y & u1z & u1w
                      & u2x & u2y & u2z & u2w & u3x & u3y & u3z & u3w
                      & u4x & u4y & u4z & u4w;
        unsigned or_  = u0x | u0y | u0z | u0w | u1x | u1y | u1z | u1w
                      | u2x | u2y | u2z | u2w | u3x | u3y | u3z | u3w
                      | u4x | u4y | u4z | u4w;
        if (ptag ? (and_ >> 31) : !(or_ >> 31)) break;
        __builtin_amdgcn_s_sleep(1);
    }
    return (((fabsf(a0.x) + fabsf(a0.y)) + (fabsf(a0.z) + fabsf(a0.w)))
          + ((fabsf(a1.x) + fabsf(a1.y)) + (fabsf(a1.z) + fabsf(a1.w))))
         + (((fabsf(a2.x) + fabsf(a2.y)) + (fabsf(a2.z) + fabsf(a2.w)))
          + ((fabsf(a3.x) + fabsf(a3.y)) + (fabsf(a3.z) + fabsf(a3.w))))
         + ((fabsf(a4.x) + fabsf(a4.y)) + (fabsf(a4.z) + fabsf(a4.w)));
}

// Poll one dwordx4 of tagged u values until all 4 sign bits == ptag.
__device__ __forceinline__ f32x4 poll_u4(const float* p, unsigned ptag) {
    f32x4 a;
    while (true) {
        a = ldg_coh4(p);
        wait_vm0();
        unsigned ax = __float_as_uint(a.x), ay = __float_as_uint(a.y),
                 az = __float_as_uint(a.z), aw = __float_as_uint(a.w);
        unsigned and_ = ax & ay & az & aw;
        unsigned or_  = ax | ay | az | aw;
        if (ptag ? (and_ >> 31) : !(or_ >> 31)) break;
        __builtin_amdgcn_s_sleep(1);
    }
    return a;
}

// legacy counter barrier (DT role only, 8 blocks)
__device__ __forceinline__ void gbar(int* ctr, int n, int tid) {
    __syncthreads();
    if (tid == 0) {
        __hip_atomic_fetch_add(ctr, 1, __ATOMIC_RELEASE, __HIP_MEMORY_SCOPE_AGENT);
        while (__hip_atomic_load(ctr, __ATOMIC_ACQUIRE, __HIP_MEMORY_SCOPE_AGENT) < n)
            __builtin_amdgcn_s_sleep(1);
    }
    __syncthreads();
}

__device__ __forceinline__ float agent_ldf(const float* p) {
    return __hip_atomic_load(p, __ATOMIC_RELAXED, __HIP_MEMORY_SCOPE_AGENT);
}

// ---------- zeroing + row norms + word-softmax partials + topic softmax ----------
__global__ void k_pre(const float* __restrict__ we, const float* __restrict__ de,
                      const float* __restrict__ te, const float* __restrict__ wwgt,
                      const float* __restrict__ twgt, float* ws) {
    __shared__ float red[256];
    int tid = threadIdx.x, b = blockIdx.x;
    int gid = b * 256 + tid;
    if (gid < 2 * NITER * T) ws[OFF_ACC + gid] = 0.f;      // ACC + ACCDT contiguous
    if (gid < 16) ws[OFF_DBL + gid] = 0.f;
    if (gid < 2) ((int*)ws)[OFF_FLAG + gid] = 0;
    if (gid < 2 * NITER) ((int*)ws)[OFF_ARR + gid] = 0;    // DT barrier counters
    if (gid < 2 * T * PSTR) ws[OFF_PART + gid] = __uint_as_float(0x80000000u); // tag=1 preset
    if (gid < 256) ws[OFF_UARR + gid] = (gid < 128) ? 0.f : __uint_as_float(0x80000000u);
    {   // squared row norms
        int r = gid;
        const float* src = nullptr; float* dst = nullptr; int row = 0;
        if (r < V)              { src = we; dst = ws + OFF_WW; row = r; }
        else if (r < V + N)     { src = de; dst = ws + OFF_DD; row = r - V; }
        else if (r < V + N + T) { src = te; dst = ws + OFF_TT; row = r - V - N; }
        if (src) {
            const float4* p = (const float4*)(src + (size_t)row * E);
            float s = 0.f;
            #pragma unroll 10
            for (int i = 0; i < E / 4; i++) { float4 v = p[i]; s += v.x*v.x + v.y*v.y + v.z*v.z + v.w*v.w; }
            dst[row] = s;
        }
    }
    if (b < 118) {  // word-softmax partials
        int j = gid;
        float w = (j < V) ? wwgt[j] : -INFINITY;
        red[tid] = w; __syncthreads();
        for (int s = 128; s > 0; s >>= 1) { if (tid < s) red[tid] = fmaxf(red[tid], red[tid + s]); __syncthreads(); }
        float m = red[0]; __syncthreads();
        float e = (j < V) ? expf(w - m) : 0.f;
        red[tid] = e; __syncthreads();
        for (int s = 128; s > 0; s >>= 1) { if (tid < s) red[tid] += red[tid + s]; __syncthreads(); }
        if (tid == 0) { ws[OFF_PM + b] = m; ws[OFF_PS + b] = red[0]; }
    } else if (b == 120) {  // topic softmax -> b_dt
        float w = (tid < T) ? twgt[tid] : -INFINITY;
        red[tid] = w; __syncthreads();
        for (int s = 128; s > 0; s >>= 1) { if (tid < s) red[tid] = fmaxf(red[tid], red[tid + s]); __syncthreads(); }
        float m = red[0]; __syncthreads();
        float e = (tid < T) ? expf(w - m) : 0.f;
        red[tid] = e; __syncthreads();
        for (int s = 128; s > 0; s >>= 1) { if (tid < s) red[tid] += red[tid + s]; __syncthreads(); }
        if (tid < T) ws[OFF_BDT + tid] = e / red[0];
    }
}

// ---------- merge word-softmax partials -> b_tw ----------
__global__ void k_pre2(const float* __restrict__ wwgt, float* ws) {
    __shared__ float red[128];
    int tid = threadIdx.x, b = blockIdx.x;
    float m = (tid < 118) ? ws[OFF_PM + tid] : -INFINITY;
    if (tid < 128) red[tid] = m;
    __syncthreads();
    for (int s = 64; s > 0; s >>= 1) { if (tid < s) red[tid] = fmaxf(red[tid], red[tid + s]); __syncthreads(); }
    float mw = red[0]; __syncthreads();
    float p = (tid < 118) ? ws[OFF_PS + tid] * expf(ws[OFF_PM + tid] - mw) : 0.f;
    if (tid < 128) red[tid] = p;
    __syncthreads();
    for (int s = 64; s > 0; s >>= 1) { if (tid < s) red[tid] += red[tid + s]; __syncthreads(); }
    float Sw = red[0];
    int j = b * 256 + tid;
    if (j < V) ws[OFF_BTW + j] = expf(wwgt[j] - mw) / Sw;
}

// ---------- K_TW[j][t] = bf16(exp(-2*sqdist)), word-major stride KSTR ----------
__global__ void k_ktw(const float* __restrict__ we, const float* __restrict__ te, float* ws) {
    __shared__ float wt[8][256];
    __shared__ float tp[8][25];
    __shared__ float tts[25];
    int tid = threadIdx.x;
    int j0 = blockIdx.x * 256;
    int t0 = blockIdx.y * 25;
    int j = j0 + tid;
    int jl = (j < V) ? j : V - 1;
    float acc[25];
    #pragma unroll
    for (int i = 0; i < 25; i++) acc[i] = 0.f;
    if (tid < 25) tts[tid] = ws[OFF_TT + t0 + tid];
    for (int kk = 0; kk < E; kk += 8) {
        #pragma unroll
        for (int k = 0; k < 8; k++) wt[k][tid] = we[(size_t)jl * E + kk + k];
        if (tid < 200) { int i = tid >> 3; int k = tid & 7; tp[k][i] = te[(size_t)(t0 + i) * E + kk + k]; }
        __syncthreads();
        #pragma unroll
        for (int k = 0; k < 8; k++) {
            float w = wt[k][tid];
            #pragma unroll
            for (int i = 0; i < 25; i++) acc[i] += tp[k][i] * w;
        }
        __syncthreads();
    }
    if (j < V) {
        float wwj = ws[OFF_WW + j];
        unsigned short* kg = (unsigned short*)(ws + OFF_KTW);
        #pragma unroll
        for (int i = 0; i < 25; i++) {
            float M = tts[i] + wwj - 2.f * acc[i];
            kg[(size_t)j * KSTR + t0 + i] = f2bf(expf(-2.f * M));
        }
    }
}

// ---------- K_DT[n][t] = exp(-3*sqdist), fp32, + any-nonzero flag ----------
__global__ void k_kdt(const float* __restrict__ de, const float* __restrict__ te, float* ws) {
    int gid = blockIdx.x * 256 + threadIdx.x;
    if (gid >= N * T) return;
    int n = gid / T; int t = gid - n * T;
    const float4* dp  = (const float4*)(de + (size_t)n * E);
    const float4* tpp = (const float4*)(te + (size_t)t * E);
    float s = 0.f;
    #pragma unroll 10
    for (int i = 0; i < E / 4; i++) { float4 a = dp[i], b = tpp[i]; s += a.x*b.x + a.y*b.y + a.z*b.z + a.w*b.w; }
    float M = ws[OFF_DD + n] + ws[OFF_TT + t] - 2.f * s;
    float kv = expf(-3.f * M);
    ws[OFF_KDT + gid] = kv;
    unsigned long long m = __ballot(kv != 0.f);
    if (m && (threadIdx.x & 63) == 0) atomicOr(((int*)ws) + OFF_KDTNZ, 1);
}

// ---------- persistent fused sinkhorn ----------
// blocks 0..NBTW-1      : TW sinkhorn, WPT=3 K-rows/thread in registers.
//   per iter: poll tagged 100-float u vector (25 threads x 1 dwordx4), down-sweep,
//   up-sweep LDS reduce -> tagged topic-major partial stores.
// blocks NBTW..NBTW+127 : bow total sum (free-running, bit-identical chunking)
// blocks NBTW+128..+135 : DT sinkhorn (gated on kdtnz) + fused DT epilogue
// block  NBTW+128+NDT   : u-reducer: polls 40x100 partials, publishes tagged u.
//   This cuts coherence-point poll traffic ~30x vs all-blocks-poll-all-partials.
__global__ __launch_bounds__(256, 1) void k_sink(const float* __restrict__ bow, float* ws) {
    __shared__ float sm[256 * 26];
    __shared__ float pr[256];
    __shared__ float u_sh[100];
    __shared__ float red8[8];
    int tid = threadIdx.x, b = blockIdx.x;

    if (b >= NBTW && b < NBTW + 128) {    // ---- bow role ----
        const float4* b4 = (const float4*)bow;
        for (int k = 0; k < 96; k++) {
            size_t base = (size_t)k * 160000;
            float s = 0.f;
            for (int i = (b - NBTW) * 256 + tid; i < 160000; i += 128 * 256) {
                float4 x = b4[base + i]; s += (x.x + x.y) + (x.z + x.w);
            }
            float bs = brsum(s, red8);
            if (tid == 0) atomicAdd((double*)(ws + OFF_DBL) + 3, (double)bs);
        }
        return;
    }

    if (b >= NBTW + 128 && b < NBTW + 128 + NDT) {   // ---- DT role (gated) ----
        if (((volatile int*)ws)[OFF_KDTNZ] == 0) return;
        int* arr = ((int*)ws) + OFF_ARR;
        int d = (b - (NBTW + 128)) * 256 + tid;    // 0..2047
        const float* Kr = ws + OFF_KDT + (size_t)d * T;
        for (int k = 0; k < NITER; k++) {
            if (tid < T) u_sh[tid] = (k == 0) ? 0.f
                : ws[OFF_BDT + tid] / (agent_ldf(ws + OFF_ACCDT + (k - 1) * T + tid) + EPS_OT);
            __syncthreads();
            float u;
            if (k == 0) u = 1.f / N;
            else {
                float s = 0.f;
                #pragma unroll 4
                for (int t = 0; t < T; t++) s += Kr[t] * u_sh[t];
                u = (1.f / N) / (s + EPS_OT);
            }
            #pragma unroll
            for (int c = 0; c < 4; c++) {
                #pragma unroll
                for (int i = 0; i < 25; i++) sm[tid * 26 + i] = Kr[25 * c + i] * u;
                __syncthreads();
                int g = tid >> 5, tl = tid & 31;
                float s2 = 0.f;
                if (tl < 25) {
                    #pragma unroll 8
                    for (int q = 0; q < 32; q++) s2 += sm[(g * 32 + q) * 26 + tl];
                }
                pr[g * 32 + tl] = s2;
                __syncthreads();
                if (tid < 25) {
                    float r = 0.f;
                    #pragma unroll
                    for (int g2 = 0; g2 < 8; g2++) r += pr[g2 * 32 + tid];
                    atomicAdd(&ws[OFF_ACCDT + k * T + 25 * c + tid], r);
                }
                __syncthreads();
            }
            gbar(arr + NITER + k, NDT, tid);
        }
        if (tid < T) {
            float vf = ws[OFF_BDT + tid] / (agent_ldf(ws + OFF_ACCDT + (NITER - 1) * T + tid) + EPS_OT);
            u_sh[tid] = vf;
            if (b == NBTW + 128) ws[OFF_VDT + tid] = vf;
        }
        __syncthreads();
        float s = 0.f;
        #pragma unroll 4
        for (int t = 0; t < T; t++) s += Kr[t] * u_sh[t];
        float u = (1.f / N) / (s + EPS_OT);
        ws[OFF_UDT + d] = u;
        float ld = 0.f; int nz = 0;
        for (int t = 0; t < T; t++) {
            float kv = Kr[t];
            if (kv > 0.f) ld += u * kv * u_sh[t] * (-(1.f / 3.f) * logf(kv));
            if ((float)N * u * kv * u_sh[t] != 0.f) nz = 1;
        }
        float ldb = brsum(ld, red8);
        if (tid == 0) atomicAdd((double*)(ws + OFF_DBL) + 1, (double)ldb);
        if (nz) atomicOr(((int*)ws) + OFF_FLAG, 1);
        return;
    }

    if (b >= NBTW + 128 + NDT) {          // ---- u-reducer block ----
        for (int k = 1; k <= NITER; k++) {
            float rs = 0.f;
            if (tid < 2 * T) {
                int t = tid >> 1, half = tid & 1;
                const float* Pp = ws + OFF_PART + (size_t)((k - 1) & 1) * (T * PSTR)
                                  + t * PSTR + half * 20;
                rs = poll_sum20(Pp, ((k - 1) >> 1) & 1);
            }
            pr[tid] = rs;
            __syncthreads();
            if (tid < T) u_sh[tid] = 0.01f / ((pr[2 * tid] + pr[2 * tid + 1]) + EPS_OT);
            __syncthreads();
            unsigned usign = (unsigned)((k >> 1) & 1) << 31;
            if (tid < 25) {
                f32x4 uv;
                uv.x = __uint_as_float(__float_as_uint(u_sh[4 * tid + 0]) | usign);
                uv.y = __uint_as_float(__float_as_uint(u_sh[4 * tid + 1]) | usign);
                uv.z = __uint_as_float(__float_as_uint(u_sh[4 * tid + 2]) | usign);
                uv.w = __uint_as_float(__float_as_uint(u_sh[4 * tid + 3]) | usign);
                stg_coh4(ws + OFF_UARR + (size_t)(k & 1) * 128 + 4 * tid, uv);
            }
            __syncthreads();
        }
        return;
    }

    // ---- TW role ----
    const unsigned short* kg = (const unsigned short*)(ws + OFF_KTW);
    unsigned ku[WPT][50];
    float bj[WPT];
    #pragma unroll
    for (int w = 0; w < WPT; w++) {
        int j = (b * WPT + w) * 256 + tid;
        bool oob = (j >= V);
        load_krow(kg, oob ? V - 1 : j, ku[w]);
        if (oob) {
            #pragma unroll
            for (int q = 0; q < 50; q++) ku[w][q] = 0;
        }
        bj[w] = oob ? 0.f : ws[OFF_BTW + j];
    }
    float v[WPT];
    #pragma unroll
    for (int w = 0; w < WPT; w++) v[w] = 0.f;

    for (int k = 0; k < NITER; k++) {
        // ---- u for iter k: poll tagged u vector from reducer (25 threads) ----
        if (k == 0) {
            if (tid < T) u_sh[tid] = 0.01f;
        } else if (tid < 25) {
            f32x4 a = poll_u4(ws + OFF_UARR + (size_t)(k & 1) * 128 + 4 * tid, (k >> 1) & 1);
            u_sh[4 * tid + 0] = fabsf(a.x);
            u_sh[4 * tid + 1] = fabsf(a.y);
            u_sh[4 * tid + 2] = fabsf(a.z);
            u_sh[4 * tid + 3] = fabsf(a.w);
        }
        __syncthreads();
        // ---- down-sweep: v_j = b_j / (K u) ----
        #pragma unroll
        for (int w = 0; w < WPT; w++) {
            float s = 0.f;
            #pragma unroll
            for (int q = 0; q < 50; q++)
                s += LOBF(ku[w][q]) * u_sh[2 * q] + HIBF(ku[w][q]) * u_sh[2 * q + 1];
            v[w] = bj[w] / (s + EPS_OT);
        }
        if (k == NITER - 1) {
            #pragma unroll
            for (int w = 0; w < WPT; w++) {
                int j = (b * WPT + w) * 256 + tid;
                if (j < V) ws[OFF_VTW + j] = v[w];
            }
        }
        // ---- up-sweep: block partial_t = sum_j K[j][t] v_j -> tagged store ----
        float* Pw = ws + OFF_PART + (size_t)(k & 1) * (T * PSTR);
        unsigned wsign = (unsigned)((k >> 1) & 1) << 31;
        #pragma unroll
        for (int c = 0; c < 4; c++) {
            #pragma unroll
            for (int i = 0; i < 25; i++) {
                int t = 25 * c + i;
                float p = 0.f;
                #pragma unroll
                for (int w = 0; w < WPT; w++) {
                    unsigned wu = ku[w][t >> 1];
                    float kt = (t & 1) ? HIBF(wu) : LOBF(wu);
                    p += kt * v[w];
                }
                sm[tid * 26 + i] = p;
            }
            __syncthreads();
            int g = tid >> 5, tl = tid & 31;
            float s2 = 0.f;
            if (tl < 25) {
                #pragma unroll 8
                for (int q = 0; q < 32; q++) s2 += sm[(g * 32 + q) * 26 + tl];
            }
            pr[g * 32 + tl] = s2;
            __syncthreads();
            if (tid < 25) {
                float r = 0.f;
                #pragma unroll
                for (int g2 = 0; g2 < 8; g2++) r += pr[g2 * 32 + tid];
                stg_coh1(Pw + (25 * c + tid) * PSTR + b,
                         __uint_as_float(__float_as_uint(r) | wsign));
            }
            __syncthreads();
        }
        // no barrier: reducer gates progress via the tagged u vector
    }
    // ---- fused TW epilogue: final u = iter-100 u from reducer + TW loss ----
    if (tid < 25) {
        f32x4 a = poll_u4(ws + OFF_UARR + (size_t)(NITER & 1) * 128 + 4 * tid, (NITER >> 1) & 1);
        u_sh[4 * tid + 0] = fabsf(a.x);
        u_sh[4 * tid + 1] = fabsf(a.y);
        u_sh[4 * tid + 2] = fabsf(a.z);
        u_sh[4 * tid + 3] = fabsf(a.w);
    }
    __syncthreads();
    if (b == 0 && tid < T) ws[OFF_UTW + tid] = u_sh[tid];
    float lt = 0.f;
    #pragma unroll
    for (int w = 0; w < WPT; w++) {
        int j = (b * WPT + w) * 256 + tid;
        if (j < V) {
            #pragma unroll
            for (int q = 0; q < 50; q++) {
                float k0 = LOBF(ku[w][q]), k1 = HIBF(ku[w][q]);
                if (k0 > 0.f) lt += u_sh[2 * q]     * k0 * v[w] * (-0.5f * logf(k0));
                if (k1 > 0.f) lt += u_sh[2 * q + 1] * k1 * v[w] * (-0.5f * logf(k1));
            }
        }
    }
    float ltb = brsum(lt, red8);
    if (tid == 0) atomicAdd((double*)(ws + OFF_DBL) + 2, (double)ltb);
}

// ---------- DSR slow path only (theta != 0 somewhere) ----------
__global__ void k_dsr(const float* __restrict__ bow, float* ws) {
    if (*(volatile int*)(((int*)ws) + OFF_FLAG) == 0) return;
    __shared__ float th[32 * T];
    __shared__ float u2[T];
    __shared__ float vd[T];
    __shared__ float red[256];
    __shared__ int flag;
    int tid = threadIdx.x;
    int j0 = blockIdx.x * 256;
    int d0 = blockIdx.y * 32;
    if (tid < T) { vd[tid] = ws[OFF_VDT + tid]; u2[tid] = ws[OFF_UTW + tid]; }
    if (tid == 0) flag = 0;
    __syncthreads();
    bool nz = false;
    for (int idx = tid; idx < 32 * T; idx += 256) {
        int dl = idx / T; int t = idx - dl * T;
        float thv = (float)N * ws[OFF_UDT + d0 + dl] * ws[OFF_KDT + (size_t)(d0 + dl) * T + t] * vd[t];
        th[idx] = thv;
        nz |= (thv != 0.f);
    }
    if (nz) flag = 1;
    __syncthreads();
    int j = j0 + tid;
    float part = 0.f;
    const unsigned short* kg = (const unsigned short*)(ws + OFF_KTW);
    if (flag) {
        float acc[32];
        #pragma unroll
        for (int d = 0; d < 32; d++) acc[d] = 0.f;
        if (j < V) {
            float vj = ws[OFF_VTW + j];
            for (int t = 0; t < T; t++) {
                float kv = bf2f(kg[(size_t)j * KSTR + t]);
                float beta = (float)T * u2[t] * kv * vj;
                #pragma unroll
                for (int d = 0; d < 32; d++) acc[d] += th[d * T + t] * beta;
            }
            for (int d = 0; d < 32; d++)
                part += bow[(size_t)(d0 + d) * V + j] * logf(acc[d] + EPS_LOG);
        }
    } else {
        if (j < V) {
            float sb = 0.f;
            #pragma unroll 8
            for (int d = 0; d < 32; d++) sb += bow[(size_t)(d0 + d) * V + j];
            part = sb * logf(EPS_LOG);
        }
    }
    red[tid] = part; __syncthreads();
    for (int s = 128; s > 0; s >>= 1) { if (tid < s) red[tid] += red[tid + s]; __syncthreads(); }
    if (tid == 0) atomicAdd((double*)(ws + OFF_DBL) + 0, (double)red[0]);
}

// ---------- combine ----------
__global__ void k_finish(float* ws, float* out) {
    if (threadIdx.x == 0 && blockIdx.x == 0) {
        double* dbl = (double*)(ws + OFF_DBL);
        int flag = ((int*)ws)[OFF_FLAG];
        double dsr_sum = flag ? dbl[0] : dbl[3] * (double)logf(EPS_LOG);
        double ldsr = -dsr_sum / (double)N;
        double letp = dbl[1] + dbl[2];
        out[0] = (float)(ldsr + letp);
        out[1] = (float)ldsr;
        out[2] = (float)letp;
    }
}

extern "C" void kernel_launch(void* const* d_in, const int* in_sizes, int n_in,
                              void* d_out, int out_size, void* d_ws, size_t ws_size,
                              hipStream_t stream) {
    const float* bow  = (const float*)d_in[0];
    const float* de   = (const float*)d_in[1];
    const float* we   = (const float*)d_in[2];
    const float* te   = (const float*)d_in[3];
    const float* wwgt = (const float*)d_in[4];
    const float* twgt = (const float*)d_in[5];
    float* out = (float*)d_out;
    float* ws  = (float*)d_ws;

    k_pre<<<128, 256, 0, stream>>>(we, de, te, wwgt, twgt, ws);
    k_pre2<<<118, 256, 0, stream>>>(wwgt, ws);
    k_ktw<<<dim3(118, 4), 256, 0, stream>>>(we, te, ws);
    k_kdt<<<800, 256, 0, stream>>>(de, te, ws);
    // persistent dispatch: 40 TW + 128 bow + 8 DT + 1 reducer = 177 <= 256 CUs.
    k_sink<<<NBTW + 128 + NDT + 1, 256, 0, stream>>>(bow, ws);
    k_dsr<<<dim3(118, 64), 256, 0, stream>>>(bow, ws);
    k_finish<<<1, 64, 0, stream>>>(ws, out);
}